// Round 8
// baseline (888.359 us; speedup 1.0000x reference)
//
#include <hip/hip_runtime.h>
#include <stdint.h>

typedef __attribute__((ext_vector_type(8))) short bf16x8;
typedef __attribute__((ext_vector_type(8))) unsigned short u16x8;
typedef __attribute__((ext_vector_type(16))) float f32x16;
typedef __attribute__((ext_vector_type(4))) int i32x4;

static constexpr int MDIM = 8192;   // B*S
static constexpr int KDIM = 4096;   // I
static constexpr int NDIM = 11008;  // O
static constexpr int BM = 256, BN = 256, BK = 32;
static constexpr int NBX = NDIM / BN;  // 43
static constexpr int NBY = MDIM / BM;  // 32

// ---------------- prep: fused A-convert + W-dequant (verified R1-R7) ----------------

static __device__ __forceinline__ unsigned short f2bf(float f) {
  unsigned int u = __builtin_bit_cast(unsigned int, f);
  return (unsigned short)((u + 0x7FFFu + ((u >> 16) & 1u)) >> 16);
}

static __device__ __forceinline__ float fp4_val(unsigned int c) {
  unsigned int m = c & 1u, e = (c >> 1) & 3u, s = (c >> 3) & 1u;
  unsigned int bits = e ? (((126u + e) << 23) | (m << 22)) : (m ? 0x3F000000u : 0u);
  bits |= s << 31;
  return __builtin_bit_cast(float, bits);
}

static constexpr int CONV_BLOCKS = (MDIM * KDIM / 8) / 256;     // 16384
static constexpr int DEQ_BLOCKS  = (NDIM * (KDIM / 32)) / 256;  // 5504

__global__ __launch_bounds__(256) void prep_kernel(
    const float4* __restrict__ in, u16x8* __restrict__ aout,
    const int* __restrict__ pw, const int* __restrict__ sc,
    unsigned short* __restrict__ wout) {
  if (blockIdx.x < CONV_BLOCKS) {
    int i = blockIdx.x * 256 + threadIdx.x;
    float4 v0 = in[2 * (size_t)i];
    float4 v1 = in[2 * (size_t)i + 1];
    u16x8 r;
    r[0] = f2bf(v0.x); r[1] = f2bf(v0.y); r[2] = f2bf(v0.z); r[3] = f2bf(v0.w);
    r[4] = f2bf(v1.x); r[5] = f2bf(v1.y); r[6] = f2bf(v1.z); r[7] = f2bf(v1.w);
    aout[i] = r;
  } else {
    int tid = (blockIdx.x - CONV_BLOCKS) * 256 + threadIdx.x;
    int o = tid >> 7;
    int b = tid & 127;
    const i32x4* src = (const i32x4*)(pw + (size_t)o * (KDIM / 2) + b * 16);
    unsigned int e = (unsigned int)sc[(size_t)o * (KDIM / 32) + b];
    float scale = __builtin_bit_cast(float, e << 23);
    unsigned short* dst = wout + (size_t)o * KDIM + b * 32;
#pragma unroll
    for (int v = 0; v < 4; ++v) {
      i32x4 w4 = src[v];
      u16x8 r;
#pragma unroll
      for (int j = 0; j < 4; ++j) {
        unsigned int w = (unsigned int)w4[j];
        r[2 * j]     = f2bf(fp4_val(w & 0xFu) * scale);
        r[2 * j + 1] = f2bf(fp4_val((w >> 4) & 0xFu) * scale);
      }
      *(u16x8*)(dst + 8 * v) = r;
    }
  }
}

// --- GEMM: 256x256, BK=32, 4 waves x (128x128 tile, 4x4 32x32 frags), 3-slot ring ---
// Per block-K-tile: LDS = 4 waves x 16 b128-reads x 12cyc + 256 write-cyc = 1024 CU-cyc
//                 = MFMA = 4 x 32 x 32 SIMD-cyc / 4 SIMD = 1024 CU-cyc  (balanced floor)

#define GLDS16(gp, lp)                                                                  \
  __builtin_amdgcn_global_load_lds((const __attribute__((address_space(1))) void*)(gp), \
                                   (__attribute__((address_space(3))) void*)(lp), 16, 0, 0)

#define BAR() asm volatile("s_barrier" ::: "memory")

// One K-tile, slot SLOT; stages tile t+2 into slot (SLOT+2)%3.
// vmcnt ledger (8 loads/tile): entering tile t outstanding = {t,t+1} = 16;
// vmcnt(8) completes t's 8. Tail: t=126 -> 8 (both 126,127 staged), t=127 -> 0.
template <int SLOT, bool STAGE, int VN>
__device__ __forceinline__ void ktile(
    unsigned char* lds, const unsigned short*& gA, const unsigned short*& gB,
    int stq, int aBase, int bBase, int kof0, int kof1, f32x16 (&acc)[4][4]) {
  if constexpr (VN == 8) asm volatile("s_waitcnt vmcnt(8)" ::: "memory");
  else                   asm volatile("s_waitcnt vmcnt(0)" ::: "memory");
  BAR();
  if (STAGE) {
    unsigned char* da = lds + ((SLOT + 2) % 3) * 32768 + stq;
    GLDS16(gA, da);
    GLDS16(gA + (size_t)64 * KDIM, da + 4096);
    GLDS16(gA + (size_t)128 * KDIM, da + 8192);
    GLDS16(gA + (size_t)192 * KDIM, da + 12288);
    GLDS16(gB, da + 16384);
    GLDS16(gB + (size_t)64 * KDIM, da + 20480);
    GLDS16(gB + (size_t)128 * KDIM, da + 24576);
    GLDS16(gB + (size_t)192 * KDIM, da + 28672);
    gA += BK; gB += BK;
  }
  const unsigned char* sa = lds + SLOT * 32768;
  const unsigned char* sb = sa + 16384;
  bf16x8 a[4], b[4];
  // ks = 0
#pragma unroll
  for (int mf = 0; mf < 4; ++mf) a[mf] = *(const bf16x8*)(sa + aBase + mf * 2048 + kof0);
#pragma unroll
  for (int nf = 0; nf < 4; ++nf) b[nf] = *(const bf16x8*)(sb + bBase + nf * 2048 + kof0);
  __builtin_amdgcn_s_setprio(1);
#pragma unroll
  for (int mf = 0; mf < 4; ++mf)
#pragma unroll
    for (int nf = 0; nf < 4; ++nf)
      acc[mf][nf] = __builtin_amdgcn_mfma_f32_32x32x16_bf16(a[mf], b[nf], acc[mf][nf], 0, 0, 0);
  __builtin_amdgcn_s_setprio(0);
  // ks = 1
#pragma unroll
  for (int mf = 0; mf < 4; ++mf) a[mf] = *(const bf16x8*)(sa + aBase + mf * 2048 + kof1);
#pragma unroll
  for (int nf = 0; nf < 4; ++nf) b[nf] = *(const bf16x8*)(sb + bBase + nf * 2048 + kof1);
  __builtin_amdgcn_s_setprio(1);
#pragma unroll
  for (int mf = 0; mf < 4; ++mf)
#pragma unroll
    for (int nf = 0; nf < 4; ++nf)
      acc[mf][nf] = __builtin_amdgcn_mfma_f32_32x32x16_bf16(a[mf], b[nf], acc[mf][nf], 0, 0, 0);
  __builtin_amdgcn_s_setprio(0);
}

__global__ __launch_bounds__(256) void gemm_mx_kernel(
    const unsigned short* __restrict__ A,   // [MDIM][KDIM] bf16
    const unsigned short* __restrict__ Bw,  // [NDIM][KDIM] bf16
    const float* __restrict__ bias,
    float* __restrict__ C) {
  __shared__ __align__(16) unsigned char lds[3 * 32768];  // 96 KiB: 3 x (A16K + B16K)

  const int t = threadIdx.x;
  const int lane = t & 63;
  const int wave = t >> 6;
  const int wr = wave >> 1;  // 0..1 (M)
  const int wc = wave & 1;   // 0..1 (N)

  // bijective XCD swizzle (grid 1376 % 8 == 0)
  const int bid = blockIdx.x;
  const int swb = (bid & 7) * ((NBX * NBY) / 8) + (bid >> 3);
  const int by = swb / NBX;
  const int bx = swb - by * NBX;
  const int m0 = by * BM, n0 = bx * BN;

  // 32x32x16 frags: lane holds row rl, k = hi*8 + r (+16*ks). Rows 64B, 4 granules.
  const int rl = lane & 31;
  const int hi = lane >> 5;
  // Swizzle: granule' = (2ks+hi) ^ (((rl>>1) ^ (rl>>3)) & 3).
  // Audited <=2-way (free) under BOTH consecutive-16 and lane-mod-8 groupings;
  // R6 (bits{0,1}) was 4-way under cons-16, R7 (bits{1,2}) 4-way under mod-8.
  const int rb = ((rl >> 1) ^ (rl >> 3)) & 3;
  const int kof0 = ((0 + hi) ^ rb) * 16;
  const int kof1 = ((2 + hi) ^ rb) * 16;
  const int aBase = (wr * 128 + rl) * 64;  // frag stride mf: 32 rows = 2048 B
  const int bBase = (wc * 128 + rl) * 64;  // frag stride nf: 32 rows = 2048 B

  // staging: LDS linear; inverse swizzle on global source column.
  // thread t writes LDS row (t>>2) (+64/call), granule t&3;
  // source granule = (t&3) ^ rb(row), rb(row) = ((t>>3) ^ (t>>5)) & 3 (call-invariant).
  const int stq = t * 16;
  const int srow = t >> 2;  // 0..63
  const int koff = 8 * ((t & 3) ^ ((t >> 3) & 3) ^ ((t >> 5) & 3));
  const unsigned short* gA = A + (size_t)(m0 + srow) * KDIM + koff;
  const unsigned short* gB = Bw + (size_t)(n0 + srow) * KDIM + koff;

  f32x16 acc[4][4] = {};

  // prologue: stage tiles 0,1 into slots 0,1 (16 loads in flight)
#pragma unroll
  for (int p = 0; p < 2; ++p) {
    unsigned char* da = lds + p * 32768 + stq;
    GLDS16(gA, da);
    GLDS16(gA + (size_t)64 * KDIM, da + 4096);
    GLDS16(gA + (size_t)128 * KDIM, da + 8192);
    GLDS16(gA + (size_t)192 * KDIM, da + 12288);
    GLDS16(gB, da + 16384);
    GLDS16(gB + (size_t)64 * KDIM, da + 20480);
    GLDS16(gB + (size_t)128 * KDIM, da + 24576);
    GLDS16(gB + (size_t)192 * KDIM, da + 28672);
    gA += BK; gB += BK;
  }

  // tiles 0..125 (42 x 3, staging through t=125 which stages 127), then 126, 127
  for (int it = 0; it < 42; ++it) {
    ktile<0, true, 8>(lds, gA, gB, stq, aBase, bBase, kof0, kof1, acc);
    ktile<1, true, 8>(lds, gA, gB, stq, aBase, bBase, kof0, kof1, acc);
    ktile<2, true, 8>(lds, gA, gB, stq, aBase, bBase, kof0, kof1, acc);
  }
  ktile<0, false, 8>(lds, gA, gB, stq, aBase, bBase, kof0, kof1, acc);  // t=126
  ktile<1, false, 0>(lds, gA, gB, stq, aBase, bBase, kof0, kof1, acc);  // t=127

  // epilogue: 32x32 C/D layout col = lane&31, row = (reg&3) + 8*(reg>>2) + 4*(lane>>5)
#pragma unroll
  for (int nf = 0; nf < 4; ++nf) {
    const int gn = n0 + wc * 128 + nf * 32 + rl;
    const float bv = bias[gn];
#pragma unroll
    for (int mf = 0; mf < 4; ++mf) {
      const int base = m0 + wr * 128 + mf * 32 + 4 * hi;
#pragma unroll
      for (int q = 0; q < 4; ++q) {
        float* cp = C + (size_t)(base + 8 * q) * NDIM + gn;
#pragma unroll
        for (int rr = 0; rr < 4; ++rr)
          cp[(size_t)rr * NDIM] = acc[mf][nf][q * 4 + rr] + bv;
      }
    }
  }
}

extern "C" void kernel_launch(void* const* d_in, const int* in_sizes, int n_in,
                              void* d_out, int out_size, void* d_ws, size_t ws_size,
                              hipStream_t stream) {
  const float* inp  = (const float*)d_in[0];
  const float* bias = (const float*)d_in[1];
  const int* pw     = (const int*)d_in[2];
  const int* sc     = (const int*)d_in[3];
  float* out = (float*)d_out;

  unsigned short* a_bf = (unsigned short*)d_ws;
  unsigned short* w_bf = a_bf + (size_t)MDIM * KDIM;
  size_t need = ((size_t)MDIM * KDIM + (size_t)NDIM * KDIM) * sizeof(unsigned short);
  if (ws_size < need) return;

  prep_kernel<<<dim3(CONV_BLOCKS + DEQ_BLOCKS), dim3(256), 0, stream>>>(
      (const float4*)inp, (u16x8*)a_bf, pw, sc, w_bf);
  gemm_mx_kernel<<<dim3(NBX * NBY), dim3(256), 0, stream>>>(a_bf, w_bf, bias, out);
}

// Round 9
// 847.037 us; speedup vs baseline: 1.0488x; 1.0488x over previous
//
#include <hip/hip_runtime.h>
#include <stdint.h>

typedef __attribute__((ext_vector_type(8))) short bf16x8;
typedef __attribute__((ext_vector_type(8))) unsigned short u16x8;
typedef __attribute__((ext_vector_type(16))) float f32x16;
typedef __attribute__((ext_vector_type(4))) int i32x4;

static constexpr int MDIM = 8192;   // B*S
static constexpr int KDIM = 4096;   // I
static constexpr int NDIM = 11008;  // O
static constexpr int BM = 256, BN = 256, BK = 64;
static constexpr int NBX = NDIM / BN;  // 43
static constexpr int NBY = MDIM / BM;  // 32

// ---------------- prep: fused A-convert + W-dequant (verified R1-R8) ----------------

static __device__ __forceinline__ unsigned short f2bf(float f) {
  unsigned int u = __builtin_bit_cast(unsigned int, f);
  return (unsigned short)((u + 0x7FFFu + ((u >> 16) & 1u)) >> 16);
}

static __device__ __forceinline__ float fp4_val(unsigned int c) {
  unsigned int m = c & 1u, e = (c >> 1) & 3u, s = (c >> 3) & 1u;
  unsigned int bits = e ? (((126u + e) << 23) | (m << 22)) : (m ? 0x3F000000u : 0u);
  bits |= s << 31;
  return __builtin_bit_cast(float, bits);
}

static constexpr int CONV_BLOCKS = (MDIM * KDIM / 8) / 256;     // 16384
static constexpr int DEQ_BLOCKS  = (NDIM * (KDIM / 32)) / 256;  // 5504

__global__ __launch_bounds__(256) void prep_kernel(
    const float4* __restrict__ in, u16x8* __restrict__ aout,
    const int* __restrict__ pw, const int* __restrict__ sc,
    unsigned short* __restrict__ wout) {
  if (blockIdx.x < CONV_BLOCKS) {
    int i = blockIdx.x * 256 + threadIdx.x;
    float4 v0 = in[2 * (size_t)i];
    float4 v1 = in[2 * (size_t)i + 1];
    u16x8 r;
    r[0] = f2bf(v0.x); r[1] = f2bf(v0.y); r[2] = f2bf(v0.z); r[3] = f2bf(v0.w);
    r[4] = f2bf(v1.x); r[5] = f2bf(v1.y); r[6] = f2bf(v1.z); r[7] = f2bf(v1.w);
    aout[i] = r;
  } else {
    int tid = (blockIdx.x - CONV_BLOCKS) * 256 + threadIdx.x;
    int o = tid >> 7;
    int b = tid & 127;
    const i32x4* src = (const i32x4*)(pw + (size_t)o * (KDIM / 2) + b * 16);
    unsigned int e = (unsigned int)sc[(size_t)o * (KDIM / 32) + b];
    float scale = __builtin_bit_cast(float, e << 23);
    unsigned short* dst = wout + (size_t)o * KDIM + b * 32;
#pragma unroll
    for (int v = 0; v < 4; ++v) {
      i32x4 w4 = src[v];
      u16x8 r;
#pragma unroll
      for (int j = 0; j < 4; ++j) {
        unsigned int w = (unsigned int)w4[j];
        r[2 * j]     = f2bf(fp4_val(w & 0xFu) * scale);
        r[2 * j + 1] = f2bf(fp4_val((w >> 4) & 0xFu) * scale);
      }
      *(u16x8*)(dst + 8 * v) = r;
    }
  }
}

// --- GEMM: 256x256, BK=64, 4 waves x (128x128, 4x4 of 32x32), 2-slot dbuf ---
// Economy: 65.5 KFLOP per b128-read (2x the 16x16 thin-wave layout) puts the LDS
// pipe UNDER the MFMA pipe. One barrier per 64-MFMA/wave window; no fences inside
// the window so the compiler software-pipelines ds_reads under MFMAs freely.

#define GLDS16(gp, lp)                                                                  \
  __builtin_amdgcn_global_load_lds((const __attribute__((address_space(1))) void*)(gp), \
                                   (__attribute__((address_space(3))) void*)(lp), 16, 0, 0)

// One BK=64 tile from slot SLOT; stages tile t+1 into slot SLOT^1.
// Sync: single __syncthreads() per tile (vmcnt(0)+lgkmcnt(0)+barrier) at the END;
// stage is issued at the TOP so its HBM latency drains under ~2200 cyc of compute.
template <int SLOT, bool STAGE>
__device__ __forceinline__ void ktile64(
    unsigned char* lds, const unsigned short*& gA, const unsigned short*& gB,
    int stq, int aBase, int bBase, const int (&kofs)[4], f32x16 (&acc)[4][4]) {
  if (STAGE) {
    unsigned char* da = lds + (SLOT ^ 1) * 65536 + stq;
#pragma unroll
    for (int c = 0; c < 8; ++c) {
      GLDS16(gA + (size_t)(32 * c) * KDIM, da + 4096 * c);
      GLDS16(gB + (size_t)(32 * c) * KDIM, da + 32768 + 4096 * c);
    }
    gA += BK; gB += BK;
  }
  const unsigned char* sa = lds + SLOT * 65536;
  const unsigned char* sb = sa + 32768;
#pragma unroll
  for (int ks = 0; ks < 4; ++ks) {
    bf16x8 a[4], b[4];
#pragma unroll
    for (int mf = 0; mf < 4; ++mf) a[mf] = *(const bf16x8*)(sa + aBase + mf * 4096 + kofs[ks]);
#pragma unroll
    for (int nf = 0; nf < 4; ++nf) b[nf] = *(const bf16x8*)(sb + bBase + nf * 4096 + kofs[ks]);
#pragma unroll
    for (int mf = 0; mf < 4; ++mf)
#pragma unroll
      for (int nf = 0; nf < 4; ++nf)
        acc[mf][nf] = __builtin_amdgcn_mfma_f32_32x32x16_bf16(a[mf], b[nf], acc[mf][nf], 0, 0, 0);
  }
  __syncthreads();
}

__global__ __launch_bounds__(256) void gemm_mx_kernel(
    const unsigned short* __restrict__ A,   // [MDIM][KDIM] bf16
    const unsigned short* __restrict__ Bw,  // [NDIM][KDIM] bf16
    const float* __restrict__ bias,
    float* __restrict__ C) {
  __shared__ __align__(16) unsigned char lds[2 * 65536];  // 2 x (A 32K + B 32K)

  const int t = threadIdx.x;
  const int lane = t & 63;
  const int wave = t >> 6;
  const int wr = wave >> 1;  // 0..1 (M)
  const int wc = wave & 1;   // 0..1 (N)

  // bijective XCD swizzle (grid 1376 % 8 == 0)
  const int bid = blockIdx.x;
  const int swb = (bid & 7) * ((NBX * NBY) / 8) + (bid >> 3);
  const int by = swb / NBX;
  const int bx = swb - by * NBX;
  const int m0 = by * BM, n0 = bx * BN;

  // 32x32x16 frags: lane holds row rl, k = hi*8 + r (+16*ks).  Rows are 128 B
  // (8 x 16B granules, BK=64).  Swizzle: granule' = (2ks+hi) ^ ((row>>1)&7).
  // 16-lane-group audit: slot(256B window) = 8*(row&1) + granule'; even rows give
  // row>>1 = 0..7 distinct, odd rows likewise -> all 16 slots distinct -> 0-conflict.
  const int rl = lane & 31;
  const int hi = lane >> 5;
  const int rbits = (rl >> 1) & 7;   // all frag row-bases are == 0 mod 16 rows
  int kofs[4];
#pragma unroll
  for (int ks = 0; ks < 4; ++ks) kofs[ks] = ((2 * ks + hi) ^ rbits) * 16;
  const int aBase = (wr * 128 + rl) * 128;  // frag stride mf: 32 rows = 4096 B
  const int bBase = (wc * 128 + rl) * 128;  // frag stride nf: 32 rows = 4096 B

  // staging: thread t -> LDS row t>>3 (+32/call), granule t&7 (linear);
  // inverse swizzle on global column: src granule = (t&7) ^ ((row>>1)&7),
  // (row>>1)&7 = (t>>4)&7 (call-invariant: rows advance by 32 == 0 mod 16).
  const int stq = t * 16;
  const int srow = t >> 3;  // 0..31
  const int koff = 8 * ((t & 7) ^ ((t >> 4) & 7));
  const unsigned short* gA = A + (size_t)(m0 + srow) * KDIM + koff;
  const unsigned short* gB = Bw + (size_t)(n0 + srow) * KDIM + koff;

  f32x16 acc[4][4] = {};

  // prologue: stage tile 0 -> slot 0
  {
    unsigned char* da = lds + stq;
#pragma unroll
    for (int c = 0; c < 8; ++c) {
      GLDS16(gA + (size_t)(32 * c) * KDIM, da + 4096 * c);
      GLDS16(gB + (size_t)(32 * c) * KDIM, da + 32768 + 4096 * c);
    }
    gA += BK; gB += BK;
    __syncthreads();
  }

  // 64 K-tiles: t=0..62 stage t+1, t=63 drains
  for (int it = 0; it < 31; ++it) {
    ktile64<0, true>(lds, gA, gB, stq, aBase, bBase, kofs, acc);
    ktile64<1, true>(lds, gA, gB, stq, aBase, bBase, kofs, acc);
  }
  ktile64<0, true>(lds, gA, gB, stq, aBase, bBase, kofs, acc);   // t=62, stages 63
  ktile64<1, false>(lds, gA, gB, stq, aBase, bBase, kofs, acc);  // t=63

  // epilogue: 32x32 C/D layout col = lane&31, row = (reg&3) + 8*(reg>>2) + 4*(lane>>5)
  // (verified R6-R8)
#pragma unroll
  for (int nf = 0; nf < 4; ++nf) {
    const int gn = n0 + wc * 128 + nf * 32 + rl;
    const float bv = bias[gn];
#pragma unroll
    for (int mf = 0; mf < 4; ++mf) {
      const int base = m0 + wr * 128 + mf * 32 + 4 * hi;
#pragma unroll
      for (int q = 0; q < 4; ++q) {
        float* cp = C + (size_t)(base + 8 * q) * NDIM + gn;
#pragma unroll
        for (int rr = 0; rr < 4; ++rr)
          cp[(size_t)rr * NDIM] = acc[mf][nf][q * 4 + rr] + bv;
      }
    }
  }
}

extern "C" void kernel_launch(void* const* d_in, const int* in_sizes, int n_in,
                              void* d_out, int out_size, void* d_ws, size_t ws_size,
                              hipStream_t stream) {
  const float* inp  = (const float*)d_in[0];
  const float* bias = (const float*)d_in[1];
  const int* pw     = (const int*)d_in[2];
  const int* sc     = (const int*)d_in[3];
  float* out = (float*)d_out;

  unsigned short* a_bf = (unsigned short*)d_ws;
  unsigned short* w_bf = a_bf + (size_t)MDIM * KDIM;
  size_t need = ((size_t)MDIM * KDIM + (size_t)NDIM * KDIM) * sizeof(unsigned short);
  if (ws_size < need) return;

  prep_kernel<<<dim3(CONV_BLOCKS + DEQ_BLOCKS), dim3(256), 0, stream>>>(
      (const float4*)inp, (u16x8*)a_bf, pw, sc, w_bf);
  gemm_mx_kernel<<<dim3(NBX * NBY), dim3(256), 0, stream>>>(a_bf, w_bf, bias, out);
}

// Round 10
// 829.854 us; speedup vs baseline: 1.0705x; 1.0207x over previous
//
#include <hip/hip_runtime.h>
#include <stdint.h>

typedef __attribute__((ext_vector_type(8))) short bf16x8;
typedef __attribute__((ext_vector_type(8))) unsigned short u16x8;
typedef __attribute__((ext_vector_type(4))) float f32x4;
typedef __attribute__((ext_vector_type(4))) int i32x4;

static constexpr int MDIM = 8192;   // B*S
static constexpr int KDIM = 4096;   // I
static constexpr int NDIM = 11008;  // O
static constexpr int BM = 256, BN = 256, BK = 32;
static constexpr int NBX = NDIM / BN;  // 43
static constexpr int NBY = MDIM / BM;  // 32

// ---------------- prep: fused A-convert + W-dequant (verified R1-R9) ----------------

static __device__ __forceinline__ unsigned short f2bf(float f) {
  unsigned int u = __builtin_bit_cast(unsigned int, f);
  return (unsigned short)((u + 0x7FFFu + ((u >> 16) & 1u)) >> 16);
}

static __device__ __forceinline__ float fp4_val(unsigned int c) {
  unsigned int m = c & 1u, e = (c >> 1) & 3u, s = (c >> 3) & 1u;
  unsigned int bits = e ? (((126u + e) << 23) | (m << 22)) : (m ? 0x3F000000u : 0u);
  bits |= s << 31;
  return __builtin_bit_cast(float, bits);
}

static constexpr int CONV_BLOCKS = (MDIM * KDIM / 8) / 256;     // 16384
static constexpr int DEQ_BLOCKS  = (NDIM * (KDIM / 32)) / 256;  // 5504

__global__ __launch_bounds__(256) void prep_kernel(
    const float4* __restrict__ in, u16x8* __restrict__ aout,
    const int* __restrict__ pw, const int* __restrict__ sc,
    unsigned short* __restrict__ wout) {
  if (blockIdx.x < CONV_BLOCKS) {
    int i = blockIdx.x * 256 + threadIdx.x;
    float4 v0 = in[2 * (size_t)i];
    float4 v1 = in[2 * (size_t)i + 1];
    u16x8 r;
    r[0] = f2bf(v0.x); r[1] = f2bf(v0.y); r[2] = f2bf(v0.z); r[3] = f2bf(v0.w);
    r[4] = f2bf(v1.x); r[5] = f2bf(v1.y); r[6] = f2bf(v1.z); r[7] = f2bf(v1.w);
    aout[i] = r;
  } else {
    int tid = (blockIdx.x - CONV_BLOCKS) * 256 + threadIdx.x;
    int o = tid >> 7;
    int b = tid & 127;
    const i32x4* src = (const i32x4*)(pw + (size_t)o * (KDIM / 2) + b * 16);
    unsigned int e = (unsigned int)sc[(size_t)o * (KDIM / 32) + b];
    float scale = __builtin_bit_cast(float, e << 23);
    unsigned short* dst = wout + (size_t)o * KDIM + b * 32;
#pragma unroll
    for (int v = 0; v < 4; ++v) {
      i32x4 w4 = src[v];
      u16x8 r;
#pragma unroll
      for (int j = 0; j < 4; ++j) {
        unsigned int w = (unsigned int)w4[j];
        r[2 * j]     = f2bf(fp4_val(w & 0xFu) * scale);
        r[2 * j + 1] = f2bf(fp4_val((w >> 4) & 0xFu) * scale);
      }
      *(u16x8*)(dst + 8 * v) = r;
    }
  }
}

// --- GEMM: R2 skeleton + cross-tile REGISTER double-buffer ---
// 256x256, BK=32, 8 waves (2Mx4N, wave-tile 128x64), 16x16x32 MFMA, acc[8][4].
// 4-slot LDS ring (128 KiB) staged 3 ahead; ONE barrier/tile at tile end.
// During tile t: issue ds_reads for tile t+1 (slot landed: end-of-(t-1) vmcnt(4)
// covered tiles t AND t+1) into the alternate frag set; MFMAs consume regs loaded
// last tile -> LDS drain hides under the MFMA window instead of serializing.

#define GLDS16(gp, lp)                                                                  \
  __builtin_amdgcn_global_load_lds((const __attribute__((address_space(1))) void*)(gp), \
                                   (__attribute__((address_space(3))) void*)(lp), 16, 0, 0)

#define BAR() asm volatile("s_barrier" ::: "memory")

// cur/nxt = [A0-3 | B0-3] fragment sets (ping-pong at call site, fully static).
// a2 = A4-7 for the CURRENT tile (loaded at the end of the previous tile).
// vmcnt ledger (4 gloads/tile, stage t+3 at tile t): end of tile t outstanding =
// {t+3} after vmcnt(4) -> tiles t+1,t+2 landed. Tail t=125: vmcnt(0).
template <int SLOT, bool STAGE, int VN, bool NEXTREAD>
__device__ __forceinline__ void ktile(
    unsigned char* lds, const unsigned short*& gA, const unsigned short*& gB,
    int stq, int aBase, int bBase, int kof,
    bf16x8 (&cur)[8], bf16x8 (&nxt)[8], bf16x8 (&a2)[4], f32x4 (&acc)[8][4]) {
  if (STAGE) {
    unsigned char* da = lds + ((SLOT + 3) & 3) * 32768 + stq;
    GLDS16(gA, da);
    GLDS16(gA + (size_t)128 * KDIM, da + 8192);
    GLDS16(gB, da + 16384);
    GLDS16(gB + (size_t)128 * KDIM, da + 24576);
    gA += BK; gB += BK;
  }
  const unsigned char* sa = lds + ((SLOT + 1) & 3) * 32768;
  const unsigned char* sb = sa + 16384;
  if (NEXTREAD) {
#pragma unroll
    for (int m = 0; m < 4; ++m) nxt[m] = *(const bf16x8*)(sa + aBase + m * 1024 + kof);
#pragma unroll
    for (int n = 0; n < 4; ++n) nxt[4 + n] = *(const bf16x8*)(sb + bBase + n * 1024 + kof);
  }
  __builtin_amdgcn_s_setprio(1);
#pragma unroll
  for (int m = 0; m < 4; ++m)
#pragma unroll
    for (int n = 0; n < 4; ++n)
      acc[m][n] = __builtin_amdgcn_mfma_f32_16x16x32_bf16(cur[m], cur[4 + n], acc[m][n], 0, 0, 0);
#pragma unroll
  for (int m = 0; m < 4; ++m)
#pragma unroll
    for (int n = 0; n < 4; ++n)
      acc[4 + m][n] = __builtin_amdgcn_mfma_f32_16x16x32_bf16(a2[m], cur[4 + n], acc[4 + m][n], 0, 0, 0);
  __builtin_amdgcn_s_setprio(0);
  if (NEXTREAD) {
#pragma unroll
    for (int m = 0; m < 4; ++m) a2[m] = *(const bf16x8*)(sa + aBase + (4 + m) * 1024 + kof);
  }
  if (VN == 4) asm volatile("s_waitcnt vmcnt(4)" ::: "memory");
  else         asm volatile("s_waitcnt vmcnt(0)" ::: "memory");
  BAR();
}

__global__ __launch_bounds__(512, 2) void gemm_mx_kernel(
    const unsigned short* __restrict__ A,   // [MDIM][KDIM] bf16
    const unsigned short* __restrict__ Bw,  // [NDIM][KDIM] bf16
    const float* __restrict__ bias,
    float* __restrict__ C) {
  __shared__ __align__(16) unsigned char lds[4 * 32768];  // 128 KiB: 4 x (A16K + B16K)

  const int t = threadIdx.x;
  const int lane = t & 63;
  const int wave = t >> 6;
  const int wr = wave >> 2;  // 0..1 (M)
  const int wc = wave & 3;   // 0..3 (N)

  // bijective XCD swizzle (grid 1376 % 8 == 0)
  const int bid = blockIdx.x;
  const int swb = (bid & 7) * ((NBX * NBY) / 8) + (bid >> 3);
  const int by = swb / NBX;
  const int bx = swb - by * NBX;
  const int m0 = by * BM, n0 = bx * BN;

  // fragment map + zero-conflict swizzle (byte-identical to R2, measured 0 conflicts)
  const int fl = lane & 15;
  const int fh = lane >> 4;
  const int kof = (fh ^ ((fl >> 1) & 3)) * 16;
  const int aBase = (wr * 128 + fl) * 64;
  const int bBase = (wc * 64 + fl) * 64;

  // staging: LDS linear (da + t*16); inverse swizzle on global source column
  const int stq = t * 16;
  const int srow = t >> 2;                          // 0..127
  const int koff = 8 * ((t & 3) ^ ((t >> 3) & 3));  // call-invariant (+128 rows == 0 mod 8)
  const unsigned short* gA = A + (size_t)(m0 + srow) * KDIM + koff;
  const unsigned short* gB = Bw + (size_t)(n0 + srow) * KDIM + koff;

  f32x4 acc[8][4] = {};
  bf16x8 r0[8], r1[8], a2[4];

  // prologue: stage tiles 0,1,2 -> slots 0,1,2; land 0,1; preload tile-0 frags
#pragma unroll
  for (int p = 0; p < 3; ++p) {
    unsigned char* da = lds + p * 32768 + stq;
    GLDS16(gA, da);
    GLDS16(gA + (size_t)128 * KDIM, da + 8192);
    GLDS16(gB, da + 16384);
    GLDS16(gB + (size_t)128 * KDIM, da + 24576);
    gA += BK; gB += BK;
  }
  asm volatile("s_waitcnt vmcnt(4)" ::: "memory");  // tiles 0,1 landed (tile 2 in flight)
  BAR();
  {
    const unsigned char* sa = lds;
    const unsigned char* sb = lds + 16384;
#pragma unroll
    for (int m = 0; m < 4; ++m) r0[m] = *(const bf16x8*)(sa + aBase + m * 1024 + kof);
#pragma unroll
    for (int n = 0; n < 4; ++n) r0[4 + n] = *(const bf16x8*)(sb + bBase + n * 1024 + kof);
#pragma unroll
    for (int m = 0; m < 4; ++m) a2[m] = *(const bf16x8*)(sa + aBase + (4 + m) * 1024 + kof);
  }

  // tiles 0..123 (31 x 4, stage t+3, prefetch t+1 frags), then tail 124..127
  for (int it = 0; it < 31; ++it) {
    ktile<0, true, 4, true>(lds, gA, gB, stq, aBase, bBase, kof, r0, r1, a2, acc);
    ktile<1, true, 4, true>(lds, gA, gB, stq, aBase, bBase, kof, r1, r0, a2, acc);
    ktile<2, true, 4, true>(lds, gA, gB, stq, aBase, bBase, kof, r0, r1, a2, acc);
    ktile<3, true, 4, true>(lds, gA, gB, stq, aBase, bBase, kof, r1, r0, a2, acc);
  }
  ktile<0, true, 4, true>(lds, gA, gB, stq, aBase, bBase, kof, r0, r1, a2, acc);    // t=124
  ktile<1, false, 0, true>(lds, gA, gB, stq, aBase, bBase, kof, r1, r0, a2, acc);   // t=125
  ktile<2, false, 0, true>(lds, gA, gB, stq, aBase, bBase, kof, r0, r1, a2, acc);   // t=126
  ktile<3, false, 0, false>(lds, gA, gB, stq, aBase, bBase, kof, r1, r0, a2, acc);  // t=127

  // epilogue: C/D layout col=lane&15, row=(lane>>4)*4+reg  [verified R1-R5]
#pragma unroll
  for (int n = 0; n < 4; ++n) {
    const int gn = n0 + wc * 64 + n * 16 + fl;
    const float bv = bias[gn];
#pragma unroll
    for (int m = 0; m < 8; ++m) {
      const int gm = m0 + wr * 128 + m * 16 + fh * 4;
      float* cp = C + (size_t)gm * NDIM + gn;
#pragma unroll
      for (int r = 0; r < 4; ++r)
        cp[(size_t)r * NDIM] = acc[m][n][r] + bv;
    }
  }
}

extern "C" void kernel_launch(void* const* d_in, const int* in_sizes, int n_in,
                              void* d_out, int out_size, void* d_ws, size_t ws_size,
                              hipStream_t stream) {
  const float* inp  = (const float*)d_in[0];
  const float* bias = (const float*)d_in[1];
  const int* pw     = (const int*)d_in[2];
  const int* sc     = (const int*)d_in[3];
  float* out = (float*)d_out;

  unsigned short* a_bf = (unsigned short*)d_ws;
  unsigned short* w_bf = a_bf + (size_t)MDIM * KDIM;
  size_t need = ((size_t)MDIM * KDIM + (size_t)NDIM * KDIM) * sizeof(unsigned short);
  if (ws_size < need) return;

  prep_kernel<<<dim3(CONV_BLOCKS + DEQ_BLOCKS), dim3(256), 0, stream>>>(
      (const float4*)inp, (u16x8*)a_bf, pw, sc, w_bf);
  gemm_mx_kernel<<<dim3(NBX * NBY), dim3(512), 0, stream>>>(a_bf, w_bf, bias, out);
}